// Round 11
// baseline (513.317 us; speedup 1.0000x reference)
//
#include <hip/hip_runtime.h>
#include <hip/hip_bf16.h>

#define BB 256
#define TT 512
#define EE 300
#define G4 200     // 4*H1
#define NPAD 208   // padded gate dim (13*16)
#define KP 1216    // proj split K'
#define KC 64
#define KPD (KP/2)
#define KCD (KC/2)
#define NCH 19
#define NT 13
#define BOFF 8192
#define BUFB 34816

typedef __attribute__((ext_vector_type(8))) short short8v;
typedef __attribute__((ext_vector_type(4))) float float4v;
typedef __attribute__((ext_vector_type(4))) unsigned int uint4v;

__device__ __forceinline__ float sigm(float x) {
    return __builtin_amdgcn_rcpf(1.f + __builtin_amdgcn_exp2f(-1.442695040888963f * x));
}
__device__ __forceinline__ float tanh_(float x) {
    float t = __builtin_amdgcn_exp2f(2.885390081777927f * x);
    return 1.f - 2.f * __builtin_amdgcn_rcpf(t + 1.f);
}

// split a into bf16 hi/lo (RNE): a ~= hi + lo
__device__ __forceinline__ uint2 bfsplit(float a) {
    unsigned u = __float_as_uint(a);
    unsigned rh = (u + 0x7FFFu + ((u >> 16) & 1u)) & 0xFFFF0000u;
    float l = a - __uint_as_float(rh);
    unsigned v = __float_as_uint(l);
    unsigned rl = (v + 0x7FFFu + ((v >> 16) & 1u)) >> 16;
    return make_uint2(rh >> 16, rl);
}

// ---------------------------------------------------------------------------
// K1: proj weights: split-bf16 B' [NPAD][KP] + permuted bias (unchanged)
__global__ void wtrans_kernel(const float* __restrict__ W, const float* __restrict__ b1,
                              unsigned* __restrict__ Btg, float* __restrict__ b1p) {
    int e = blockIdx.x;
    int j = threadIdx.x;
    if (j >= NPAD) return;
    float w = 0.f;
    if (j < G4) w = W[((j & 3) * 50 + (j >> 2)) * EE + e];
    uint2 s = bfsplit(w);
    *(uint2*)(Btg + (size_t)j * KPD + 2 * e) =
        make_uint2(s.x | (s.x << 16), s.y | (s.y << 16));
    if (e == 0) b1p[j] = (j < G4) ? b1[(j & 3) * 50 + (j >> 2)] : 0.f;
}

// ---------------------------------------------------------------------------
// K1b: lstm weights as MFMA A-fragments, split-bf16.
// 16 Mtiles (13 L1 jp=4u+g rows of W_hh1; 3 L2 rows of [W_ih2|W_hh2]) x
// 8 K-chunks of 32. A'[row][k'=4k+s] = s<2 ? Wh : Wl.
// Frag: lane l holds rows 16mt+(l&15), k' = ch*32+(l>>4)*8+j.
__global__ void wtrans2_kernel(const float* __restrict__ W_hh1, const float* __restrict__ W_ih2,
                               const float* __restrict__ W_hh2, const float* __restrict__ b2,
                               unsigned short* __restrict__ W2, float* __restrict__ b2p) {
    int gid = blockIdx.x * 256 + threadIdx.x;   // (mt*8+ch)*64 + l, 8192 total
    int mt = gid >> 9;
    int ch = (gid >> 6) & 7;
    int l  = gid & 63;
    unsigned short frag[8];
    #pragma unroll
    for (int j = 0; j < 8; ++j) {
        int kp = ch * 32 + ((l >> 4) << 3) + j;
        int k = kp >> 2, s = kp & 3;
        float w = 0.f;
        if (mt < 13) {
            int jp = 16 * mt + (l & 15);
            if (jp < 200 && k < 50) {
                int u = jp >> 2, g = jp & 3;
                w = W_hh1[(g * 50 + u) * 50 + k];
            }
        } else {
            int jq = 16 * (mt - 13) + (l & 15);
            if (jq < 40) {
                int u2 = jq >> 2, g = jq & 3;
                int row = g * 10 + u2;
                if (k < 50)      w = W_ih2[row * 50 + k];
                else if (k < 60) w = W_hh2[row * 10 + (k - 50)];
            }
        }
        uint2 sp = bfsplit(w);
        frag[j] = (unsigned short)((s < 2) ? sp.x : sp.y);
    }
    #pragma unroll
    for (int j = 0; j < 8; ++j) W2[(size_t)gid * 8 + j] = frag[j];
    if (gid < 48) b2p[gid] = (gid < 40) ? b2[(gid & 3) * 10 + (gid >> 2)] : 0.f;
}

// ---------------------------------------------------------------------------
// K2: MFMA proj (unchanged, verified).
__device__ __forceinline__ float f4get(const float4& v, int u) {
    return u == 0 ? v.x : u == 1 ? v.y : u == 2 ? v.z : v.w;
}

__global__ __launch_bounds__(256, 2) void proj_kernel(
    const int* __restrict__ x, const int* __restrict__ lengths,
    const float* __restrict__ emb, const unsigned* __restrict__ Btg,
    const float* __restrict__ b1p, float* __restrict__ G1, int b0)
{
    const int b  = b0 + blockIdx.y;
    const int t0 = blockIdx.x * 64;
    const int len = lengths[b];
    if (t0 >= len) return;

    const int tid  = threadIdx.x;
    const int wv   = tid >> 6;
    const int lane = tid & 63;

    __shared__ __align__(16) char lds[2 * BUFB];

    const int arow = tid >> 2;
    const int ag   = tid & 3;
    const float* er = emb + (size_t)x[b * TT + t0 + arow] * EE;

    float4v acc[NT] = {};

    auto stageB = [&](int c, int q) {
        char* base = lds + q * BUFB + BOFF;
        #pragma unroll
        for (int rr = 0; rr < 7; ++rr) {
            if (rr < 6 || tid < 128) {
                int g   = rr * 256 + tid;
                int row = g >> 3, sl = g & 7;
                const unsigned* src = Btg + (size_t)row * KPD + c * KCD
                                      + ((sl ^ (row & 7)) << 2);
                char* dst = base + (rr * 256 + (tid & ~63)) * 16;
                __builtin_amdgcn_global_load_lds(
                    (const __attribute__((address_space(1))) void*)src,
                    (__attribute__((address_space(3))) void*)dst, 16, 0, 0);
            }
        }
    };
    auto loadA = [&](int cc) -> float4 {
        int k0 = cc * 16 + ag * 4;
        if (k0 < EE) return *(const float4*)(er + k0);
        return make_float4(0.f, 0.f, 0.f, 0.f);
    };
    auto writeA = [&](int q, float4 av) {
        uint2 s0 = bfsplit(av.x), s1 = bfsplit(av.y);
        uint2 s2 = bfsplit(av.z), s3 = bfsplit(av.w);
        unsigned p0 = s0.x | (s0.y << 16), p1 = s1.x | (s1.y << 16);
        unsigned p2 = s2.x | (s2.y << 16), p3 = s3.x | (s3.y << 16);
        char* base = lds + q * BUFB + (arow << 7);
        int r7 = arow & 7;
        *(uint4v*)(base + ((( 2 * ag    ) ^ r7) << 4)) = uint4v{p0, p0, p1, p1};
        *(uint4v*)(base + (((2 * ag + 1) ^ r7) << 4)) = uint4v{p2, p2, p3, p3};
    };

    stageB(0, 0);
    float4 aval = loadA(0);
    asm volatile("s_waitcnt vmcnt(0)" ::: "memory");
    writeA(0, aval);
    asm volatile("s_waitcnt lgkmcnt(0)" ::: "memory");
    __builtin_amdgcn_s_barrier();
    __builtin_amdgcn_sched_barrier(0);

    int p = 0;
    for (int c = 0; c < NCH; ++c) {
        const int q = p ^ 1;
        if (c + 1 < NCH) {
            stageB(c + 1, q);
            aval = loadA(c + 1);
        }
        const int r  = lane & 15;
        const int h  = lane >> 4;
        #pragma unroll
        for (int s = 0; s < 2; ++s) {
            const int sw4 = (((4 * s + h) ^ (r & 7)) << 4);
            short8v aF = *(const short8v*)(lds + p * BUFB + ((wv * 16 + r) << 7) + sw4);
            #pragma unroll
            for (int nt = 0; nt < NT; ++nt) {
                short8v bF = *(const short8v*)(lds + p * BUFB + BOFF
                                               + ((nt * 16 + r) << 7) + sw4);
                acc[nt] = __builtin_amdgcn_mfma_f32_16x16x32_bf16(aF, bF, acc[nt], 0, 0, 0);
            }
        }
        if (c + 1 < NCH) {
            asm volatile("s_waitcnt vmcnt(0)" ::: "memory");
            writeA(q, aval);
            asm volatile("s_waitcnt lgkmcnt(0)" ::: "memory");
            __builtin_amdgcn_s_barrier();
            __builtin_amdgcn_sched_barrier(0);
        }
        p = q;
    }

    float* gbase = G1 + ((size_t)blockIdx.y * TT + t0) * G4;
    const int col = lane & 15, rq = lane >> 4;
    #pragma unroll
    for (int nt = 0; nt < NT; ++nt) {
        int jp = nt * 16 + col;
        if (jp < G4) {
            float bias = b1p[jp];
            #pragma unroll
            for (int rr = 0; rr < 4; ++rr)
                gbase[(size_t)(wv * 16 + rq * 4 + rr) * G4 + jp] = acc[nt][rr] + bias;
        }
    }
}

// ---------------------------------------------------------------------------
// K3: MFMA recurrence. One block (512 thr = 8 waves) per 16 batch elements.
// Wave w owns Mtiles {2w,2w+1} (13 L1 + 3 L2). Per step: acc init from G1
// (L1, prefetched) or b2p (L2); 8 K-chunk MFMAs per Mtile with W' frags held
// in VGPRs and h' B-frags read from swizzled LDS; lane-local cell update
// (lane = one unit, one batch col); split-bf16 h written back; 1 barrier.
// L2 lags one step; loop runs LMAX+1 iters with per-lane freeze predicates.
__global__ __launch_bounds__(512, 1) void lstm_kernel(
    const int* __restrict__ lengths,
    const unsigned short* __restrict__ W2, const float* __restrict__ b2p,
    const float* __restrict__ fc1w, const float* __restrict__ fc1b,
    const float* __restrict__ fc2w, const float* __restrict__ fc2b,
    const float* __restrict__ G1, float* __restrict__ out, int b0, int nb)
{
    const int tid  = threadIdx.x;
    const int wv   = tid >> 6;
    const int lane = tid & 63;
    const int b    = lane & 15;
    const int q    = lane >> 4;
    const int mt0  = 2 * wv, mt1 = 2 * wv + 1;

    const int last = b0 + nb - 1;
    int eg = b0 + blockIdx.x * 16 + b;
    if (eg > last) eg = last;
    const int mylen = lengths[eg];

    int LMAX = 1;
    for (int k = 0; k < 16; ++k) {
        int e2 = b0 + blockIdx.x * 16 + k;
        if (e2 > last) e2 = last;
        int L = lengths[e2];
        if (L > LMAX) LMAX = L;
    }

    __shared__ __align__(16) char hbuf[2][8192];   // [buf][b][64 units][8B], swizzled
    __shared__ float hfin[16][12];

    {   // zero-init hbuf (covers pad units; frozen slots stay valid forever)
        uint4v* z = (uint4v*)hbuf;
        z[2 * tid] = uint4v{0, 0, 0, 0};
        z[2 * tid + 1] = uint4v{0, 0, 0, 0};
    }

    // W' fragments: 2 Mtiles x 8 chunks, resident in VGPRs
    const short8v* w2v = (const short8v*)W2;
    short8v wf0[8], wf1[8];
    #pragma unroll
    for (int c = 0; c < 8; ++c) wf0[c] = w2v[(mt0 * 8 + c) * 64 + lane];
    #pragma unroll
    for (int c = 0; c < 8; ++c) wf1[c] = w2v[(mt1 * 8 + c) * 64 + lane];

    const bool L1a = (mt0 < 13), L1b = (mt1 < 13);
    const int ua = L1a ? (4 * mt0 + q) : (50 + 4 * (mt0 - 13) + q);   // hbuf slot
    const int ub = L1b ? (4 * mt1 + q) : (50 + 4 * (mt1 - 13) + q);
    const bool va = L1a ? (4 * mt0 + q < 50) : (4 * (mt0 - 13) + q < 10);
    const bool vb = L1b ? (4 * mt1 + q < 50) : (4 * (mt1 - 13) + q < 10);

    float4 binit_a = make_float4(0.f, 0.f, 0.f, 0.f);
    float4 binit_b = make_float4(0.f, 0.f, 0.f, 0.f);
    if (!L1a) binit_a = *(const float4*)(b2p + 16 * (mt0 - 13) + 4 * q);
    if (!L1b) binit_b = *(const float4*)(b2p + 16 * (mt1 - 13) + 4 * q);

    const float* gpa = G1 + (size_t)(eg - b0) * TT * G4 + 16 * mt0 + 4 * q;
    const float* gpb = G1 + (size_t)(eg - b0) * TT * G4 + 16 * mt1 + 4 * q;

    float4 fa0 = binit_a, fa1 = binit_a, fa2 = binit_a;
    float4 fb0 = binit_b, fb1 = binit_b, fb2 = binit_b;
    {
        int t1 = (1 < mylen) ? 1 : mylen - 1;
        int t2 = (2 < mylen) ? 2 : mylen - 1;
        if (L1a) {
            fa0 = *(const float4*)(gpa);
            fa1 = *(const float4*)(gpa + (size_t)t1 * G4);
            fa2 = *(const float4*)(gpa + (size_t)t2 * G4);
        }
        if (L1b) {
            fb0 = *(const float4*)(gpb);
            fb1 = *(const float4*)(gpb + (size_t)t1 * G4);
            fb2 = *(const float4*)(gpb + (size_t)t2 * G4);
        }
    }

    float ca = 0.f, ha = 0.f, cb = 0.f, hb2 = 0.f;
    const int rbyte0 = b * 512 + (q * 2) * 8;       // chunk c adds c*64
    const int swz    = (b & 7) << 4;
    const int wba    = (b * 512 + ua * 8) ^ swz;
    const int wbb    = (b * 512 + ub * 8) ^ swz;

    __syncthreads();

    int pb = 0;
    for (int i = 0; i <= LMAX; ++i) {
        float4 ga = fa0; fa0 = fa1; fa1 = fa2;
        float4 gb = fb0; fb0 = fb1; fb1 = fb2;
        int tn = (i + 3 < mylen) ? i + 3 : mylen - 1;
        if (L1a) fa2 = *(const float4*)(gpa + (size_t)tn * G4);   // stays in flight
        if (L1b) fb2 = *(const float4*)(gpb + (size_t)tn * G4);

        float4v acc0 = {ga.x, ga.y, ga.z, ga.w};
        float4v acc1 = {gb.x, gb.y, gb.z, gb.w};

        const char* hbp = hbuf[pb];
        short8v bf[8];
        #pragma unroll
        for (int c = 0; c < 8; ++c)
            bf[c] = *(const short8v*)(hbp + ((rbyte0 + c * 64) ^ swz));
        #pragma unroll
        for (int c = 0; c < 8; ++c) {
            acc0 = __builtin_amdgcn_mfma_f32_16x16x32_bf16(wf0[c], bf[c], acc0, 0, 0, 0);
            acc1 = __builtin_amdgcn_mfma_f32_16x16x32_bf16(wf1[c], bf[c], acc1, 0, 0, 0);
        }

        // lane-local cell updates (gates i,f,g,o = acc[0..3])
        {
            bool upd = va && (L1a ? (i < mylen) : (i >= 1 && i - 1 < mylen));
            float cn = sigm(acc0[1]) * ca + sigm(acc0[0]) * tanh_(acc0[2]);
            float hn = sigm(acc0[3]) * tanh_(cn);
            if (upd) { ca = cn; ha = hn; }
        }
        {
            bool upd = vb && (L1b ? (i < mylen) : (i >= 1 && i - 1 < mylen));
            float cn = sigm(acc1[1]) * cb + sigm(acc1[0]) * tanh_(acc1[2]);
            float hn = sigm(acc1[3]) * tanh_(cn);
            if (upd) { cb = cn; hb2 = hn; }
        }

        // write h (split bf16, B'-packed) to the other buffer
        char* hwp = hbuf[pb ^ 1];
        if (va) {
            uint2 sp = bfsplit(ha);
            unsigned d = sp.x | (sp.y << 16);
            *(uint2*)(hwp + wba) = make_uint2(d, d);
        }
        if (vb) {
            uint2 sp = bfsplit(hb2);
            unsigned d = sp.x | (sp.y << 16);
            *(uint2*)(hwp + wbb) = make_uint2(d, d);
        }

        asm volatile("s_waitcnt lgkmcnt(0)" ::: "memory");
        __builtin_amdgcn_s_barrier();
        __builtin_amdgcn_sched_barrier(0);
        pb ^= 1;
    }

    // h2 finals live in L2 lanes' registers
    if (!L1a && va) hfin[b][4 * (mt0 - 13) + q] = ha;
    if (!L1b && vb) hfin[b][4 * (mt1 - 13) + q] = hb2;
    __syncthreads();

    // MLP head: one lane per batch column
    if (tid < 16) {
        int eo = b0 + blockIdx.x * 16 + tid;
        if (eo <= last) {
            float o = fc2b[0];
            #pragma unroll
            for (int j = 0; j < 10; ++j) {
                float s = fc1b[j];
                #pragma unroll
                for (int k = 0; k < 10; ++k)
                    s = fmaf(fc1w[j * 10 + k], hfin[tid][k], s);
                o = fmaf(fc2w[j], s > 0.f ? s : 0.f, o);
            }
            out[eo] = o;
        }
    }
}

// ---------------------------------------------------------------------------
extern "C" void kernel_launch(void* const* d_in, const int* in_sizes, int n_in,
                              void* d_out, int out_size, void* d_ws, size_t ws_size,
                              hipStream_t stream)
{
    const int*   x     = (const int*)  d_in[0];
    const int*   len   = (const int*)  d_in[1];
    const float* emb   = (const float*)d_in[2];
    const float* W_ih1 = (const float*)d_in[3];
    const float* W_hh1 = (const float*)d_in[4];
    const float* b1    = (const float*)d_in[5];
    const float* W_ih2 = (const float*)d_in[6];
    const float* W_hh2 = (const float*)d_in[7];
    const float* b2    = (const float*)d_in[8];
    const float* fc1w  = (const float*)d_in[9];
    const float* fc1b  = (const float*)d_in[10];
    const float* fc2w  = (const float*)d_in[11];
    const float* fc2b  = (const float*)d_in[12];
    float* out = (float*)d_out;

    const size_t btg_bytes = (size_t)NPAD * KPD * sizeof(unsigned);   // 505856
    const size_t b1p_off = btg_bytes;                                 // 505856
    const size_t b2p_off = b1p_off + 208 * sizeof(float);             // 506688
    const size_t w2_off  = (b2p_off + 48 * sizeof(float) + 15) & ~15ull; // 506880
    const size_t w2_bytes = 8192ull * 8 * sizeof(unsigned short);     // 131072
    const size_t head = (w2_off + w2_bytes + 255) & ~255ull;          // 637952
    const size_t per_b = (size_t)TT * G4 * sizeof(float);             // 409600

    unsigned*       Btg = (unsigned*)d_ws;
    float*          b1p = (float*)((char*)d_ws + b1p_off);
    float*          b2p = (float*)((char*)d_ws + b2p_off);
    unsigned short* W2  = (unsigned short*)((char*)d_ws + w2_off);
    float*          G1  = (float*)((char*)d_ws + head);

    size_t avail = ws_size > head ? ws_size - head : 0;
    int chunk = (int)(avail / per_b);
    chunk &= ~15;
    if (chunk < 16) chunk = 16;
    if (chunk > BB) chunk = BB;

    wtrans_kernel<<<dim3(EE), dim3(256), 0, stream>>>(W_ih1, b1, Btg, b1p);
    wtrans2_kernel<<<dim3(32), dim3(256), 0, stream>>>(W_hh1, W_ih2, W_hh2, b2, W2, b2p);

    for (int b0 = 0; b0 < BB; b0 += chunk) {
        int nb = (BB - b0) < chunk ? (BB - b0) : chunk;
        proj_kernel<<<dim3(TT / 64, nb), dim3(256), 0, stream>>>(
            x, len, emb, Btg, b1p, G1, b0);
        lstm_kernel<<<dim3((nb + 15) / 16), dim3(512), 0, stream>>>(
            len, W2, b2p, fc1w, fc1b, fc2w, fc2b, G1, out, b0, nb);
    }
}

// Round 12
// 347.750 us; speedup vs baseline: 1.4761x; 1.4761x over previous
//
#include <hip/hip_runtime.h>
#include <hip/hip_bf16.h>

#define BB 256
#define TT 512
#define EE 300
#define G4 200     // 4*H1
#define NPAD 208   // padded gate dim (13*16)
#define KP 1216    // proj split K'
#define KC 64
#define KPD (KP/2)
#define KCD (KC/2)
#define NCH 19
#define NT 13
#define BOFF 8192
#define BUFB 34816

typedef __attribute__((ext_vector_type(8))) short short8v;
typedef __attribute__((ext_vector_type(4))) float float4v;
typedef __attribute__((ext_vector_type(4))) unsigned int uint4v;

// permuted gate col: G1 column jp corresponds to W row (jp&3)*50 + (jp>>2),
// so lstm thread tid==jp has gates (i,f,g,o) of unit u=tid>>2 in its quad.

__device__ __forceinline__ float sigm(float x) {
    return __builtin_amdgcn_rcpf(1.f + __builtin_amdgcn_exp2f(-1.442695040888963f * x));
}
__device__ __forceinline__ float tanh_(float x) {
    float t = __builtin_amdgcn_exp2f(2.885390081777927f * x);   // e^(2x)
    return 1.f - 2.f * __builtin_amdgcn_rcpf(t + 1.f);
}
// quad broadcast via DPP: all 4 lanes of a quad get quad-lane C's value
template <int C>
__device__ __forceinline__ float qb(float v) {
    return __int_as_float(__builtin_amdgcn_mov_dpp(__float_as_int(v), C, 0xF, 0xF, true));
}

// split a into bf16 hi/lo (RNE): a ~= hi + lo, err ~2^-16 rel
__device__ __forceinline__ uint2 bfsplit(float a) {
    unsigned u = __float_as_uint(a);
    unsigned rh = (u + 0x7FFFu + ((u >> 16) & 1u)) & 0xFFFF0000u;
    float l = a - __uint_as_float(rh);
    unsigned v = __float_as_uint(l);
    unsigned rl = (v + 0x7FFFu + ((v >> 16) & 1u)) >> 16;
    return make_uint2(rh >> 16, rl);
}

// ---------------------------------------------------------------------------
// K1: proj weights: split-bf16 B' [NPAD][KP] + permuted bias
__global__ void wtrans_kernel(const float* __restrict__ W, const float* __restrict__ b1,
                              unsigned* __restrict__ Btg, float* __restrict__ b1p) {
    int e = blockIdx.x;
    int j = threadIdx.x;
    if (j >= NPAD) return;
    float w = 0.f;
    if (j < G4) w = W[((j & 3) * 50 + (j >> 2)) * EE + e];
    uint2 s = bfsplit(w);
    *(uint2*)(Btg + (size_t)j * KPD + 2 * e) =
        make_uint2(s.x | (s.x << 16), s.y | (s.y << 16));
    if (e == 0) b1p[j] = (j < G4) ? b1[(j & 3) * 50 + (j >> 2)] : 0.f;
}

// ---------------------------------------------------------------------------
// K2: MFMA proj (verified: absmax 4.8e-7, ~80us, 0 bank conflicts).
__global__ __launch_bounds__(256, 2) void proj_kernel(
    const int* __restrict__ x, const int* __restrict__ lengths,
    const float* __restrict__ emb, const unsigned* __restrict__ Btg,
    const float* __restrict__ b1p, float* __restrict__ G1, int b0)
{
    const int b  = b0 + blockIdx.y;
    const int t0 = blockIdx.x * 64;
    const int len = lengths[b];
    if (t0 >= len) return;

    const int tid  = threadIdx.x;
    const int wv   = tid >> 6;
    const int lane = tid & 63;

    __shared__ __align__(16) char lds[2 * BUFB];

    const int arow = tid >> 2;
    const int ag   = tid & 3;
    const float* er = emb + (size_t)x[b * TT + t0 + arow] * EE;

    float4v acc[NT] = {};

    auto stageB = [&](int c, int q) {
        char* base = lds + q * BUFB + BOFF;
        #pragma unroll
        for (int rr = 0; rr < 7; ++rr) {
            if (rr < 6 || tid < 128) {
                int g   = rr * 256 + tid;
                int row = g >> 3, sl = g & 7;
                const unsigned* src = Btg + (size_t)row * KPD + c * KCD
                                      + ((sl ^ (row & 7)) << 2);
                char* dst = base + (rr * 256 + (tid & ~63)) * 16;
                __builtin_amdgcn_global_load_lds(
                    (const __attribute__((address_space(1))) void*)src,
                    (__attribute__((address_space(3))) void*)dst, 16, 0, 0);
            }
        }
    };
    auto loadA = [&](int cc) -> float4 {
        int k0 = cc * 16 + ag * 4;
        if (k0 < EE) return *(const float4*)(er + k0);
        return make_float4(0.f, 0.f, 0.f, 0.f);
    };
    auto writeA = [&](int q, float4 av) {
        uint2 s0 = bfsplit(av.x), s1 = bfsplit(av.y);
        uint2 s2 = bfsplit(av.z), s3 = bfsplit(av.w);
        unsigned p0 = s0.x | (s0.y << 16), p1 = s1.x | (s1.y << 16);
        unsigned p2 = s2.x | (s2.y << 16), p3 = s3.x | (s3.y << 16);
        char* base = lds + q * BUFB + (arow << 7);
        int r7 = arow & 7;
        *(uint4v*)(base + ((( 2 * ag    ) ^ r7) << 4)) = uint4v{p0, p0, p1, p1};
        *(uint4v*)(base + (((2 * ag + 1) ^ r7) << 4)) = uint4v{p2, p2, p3, p3};
    };

    stageB(0, 0);
    float4 aval = loadA(0);
    asm volatile("s_waitcnt vmcnt(0)" ::: "memory");
    writeA(0, aval);
    asm volatile("s_waitcnt lgkmcnt(0)" ::: "memory");
    __builtin_amdgcn_s_barrier();
    __builtin_amdgcn_sched_barrier(0);

    int p = 0;
    for (int c = 0; c < NCH; ++c) {
        const int q = p ^ 1;
        if (c + 1 < NCH) {
            stageB(c + 1, q);
            aval = loadA(c + 1);
        }
        const int r  = lane & 15;
        const int h  = lane >> 4;
        #pragma unroll
        for (int s = 0; s < 2; ++s) {
            const int sw4 = (((4 * s + h) ^ (r & 7)) << 4);
            short8v aF = *(const short8v*)(lds + p * BUFB + ((wv * 16 + r) << 7) + sw4);
            #pragma unroll
            for (int nt = 0; nt < NT; ++nt) {
                short8v bF = *(const short8v*)(lds + p * BUFB + BOFF
                                               + ((nt * 16 + r) << 7) + sw4);
                acc[nt] = __builtin_amdgcn_mfma_f32_16x16x32_bf16(aF, bF, acc[nt], 0, 0, 0);
            }
        }
        if (c + 1 < NCH) {
            asm volatile("s_waitcnt vmcnt(0)" ::: "memory");
            writeA(q, aval);
            asm volatile("s_waitcnt lgkmcnt(0)" ::: "memory");
            __builtin_amdgcn_s_barrier();
            __builtin_amdgcn_sched_barrier(0);
        }
        p = q;
    }

    float* gbase = G1 + ((size_t)blockIdx.y * TT + t0) * G4;
    const int col = lane & 15, rq = lane >> 4;
    #pragma unroll
    for (int nt = 0; nt < NT; ++nt) {
        int jp = nt * 16 + col;
        if (jp < G4) {
            float bias = b1p[jp];
            #pragma unroll
            for (int rr = 0; rr < 4; ++rr)
                gbase[(size_t)(wv * 16 + rq * 4 + rr) * G4 + jp] = acc[nt][rr] + bias;
        }
    }
}

// ---------------------------------------------------------------------------
// K3: recurrence — the R4 unified 4-wave structure (best measured).
// One block (256 thr = 4 waves) per batch element, zero divergence:
//   tid 0..199  : LSTM1 permuted row jp=tid -> W row (jp&3)*50+(jp>>2); base=G1
//   tid 200..239: LSTM2 permuted row q=tid-200 -> row (q&3)*10+(q>>2);  base=b2
//                 (lags one step: at iter i computes h2(i-1))
//   tid 240..255: inert (zero weights)
// h state in hs[2][64]: [0..49]=h1, [52..61]=h2, rest 0. One barrier/step.
__global__ __launch_bounds__(256, 1) void lstm_kernel(
    const int* __restrict__ lengths,
    const float* __restrict__ W_hh1, const float* __restrict__ W_ih2,
    const float* __restrict__ W_hh2, const float* __restrict__ b2,
    const float* __restrict__ fc1w, const float* __restrict__ fc1b,
    const float* __restrict__ fc2w, const float* __restrict__ fc2b,
    const float* __restrict__ G1, float* __restrict__ out, int b0)
{
    const int bb  = blockIdx.x;
    const int b   = b0 + bb;
    const int tid = threadIdx.x;
    const int len = lengths[b];

    __shared__ __align__(16) float hs[2][64];
    __shared__ __align__(16) float hfin[12];
    __shared__ float zbuf[10];

    if (tid < 64) { hs[0][tid] = 0.f; hs[1][tid] = 0.f; }

    const bool isL1 = (tid < 200);
    const bool isL2 = (tid >= 200 && tid < 240);

    float wreg[52];                 // L1: W_hh1 row | L2: W_ih2 row (+2 pad)
    float wregb[12];                // L2: W_hh2 row (+2 pad)
    #pragma unroll
    for (int k = 0; k < 52; ++k) wreg[k] = 0.f;
    #pragma unroll
    for (int k = 0; k < 12; ++k) wregb[k] = 0.f;
    float base2 = 0.f;

    if (isL1) {
        int u = tid >> 2, g = tid & 3;
        const float* wp = W_hh1 + (g * 50 + u) * 50;
        #pragma unroll
        for (int k = 0; k < 50; ++k) wreg[k] = wp[k];
    } else if (isL2) {
        int q = tid - 200, u = q >> 2, g = q & 3;
        int row = g * 10 + u;
        const float* wp = W_ih2 + row * 50;
        #pragma unroll
        for (int k = 0; k < 50; ++k) wreg[k] = wp[k];
        const float* wp2 = W_hh2 + row * 10;
        #pragma unroll
        for (int k = 0; k < 10; ++k) wregb[k] = wp2[k];
        base2 = b2[row];
    }

    const bool wr   = ((tid & 3) == 0) && (tid < 240);
    const int  slot = isL1 ? (tid >> 2) : (52 + ((tid - 200) >> 2));

    float h1v[52], h2v[12];
    #pragma unroll
    for (int k = 0; k < 52; ++k) h1v[k] = 0.f;
    #pragma unroll
    for (int k = 0; k < 12; ++k) h2v[k] = 0.f;

    float c = 0.f;
    const float* g1p = G1 + (size_t)bb * TT * G4;
    const int gcol = isL1 ? tid : 199;           // inert/L2: harmless clamped load
    float g0, g1r, g2r;                          // 3-deep prefetch rotation
    {
        int t1 = (1 < len) ? 1 : len - 1;
        int t2 = (2 < len) ? 2 : len - 1;
        g0  = g1p[gcol];
        g1r = g1p[(size_t)t1 * G4 + gcol];
        g2r = g1p[(size_t)t2 * G4 + gcol];
    }

    __syncthreads();                              // LDS zero-init visible

    for (int i = 0; i < len; ++i) {
        float base = isL1 ? g0 : base2;
        g0 = g1r; g1r = g2r;
        int tn = (i + 3 < len) ? i + 3 : len - 1;
        g2r = g1p[(size_t)tn * G4 + gcol];        // prefetch 3 ahead (never drained)

        float s0 = 0.f, s1 = 0.f, s2 = 0.f, s3 = 0.f;
        #pragma unroll
        for (int m = 0; m < 13; ++m) {
            s0 = fmaf(wreg[4*m+0], h1v[4*m+0], s0);
            s1 = fmaf(wreg[4*m+1], h1v[4*m+1], s1);
            s2 = fmaf(wreg[4*m+2], h1v[4*m+2], s2);
            s3 = fmaf(wreg[4*m+3], h1v[4*m+3], s3);
        }
        #pragma unroll
        for (int m = 0; m < 3; ++m) {
            s0 = fmaf(wregb[4*m+0], h2v[4*m+0], s0);
            s1 = fmaf(wregb[4*m+1], h2v[4*m+1], s1);
            s2 = fmaf(wregb[4*m+2], h2v[4*m+2], s2);
            s3 = fmaf(wregb[4*m+3], h2v[4*m+3], s3);
        }
        float gv = base + (s0 + s1) + (s2 + s3);

        float gi = qb<0x00>(gv);
        float gf = qb<0x55>(gv);
        float gg = qb<0xAA>(gv);
        float go = qb<0xFF>(gv);
        float cn = sigm(gf) * c + sigm(gi) * tanh_(gg);
        float hn = sigm(go) * tanh_(cn);
        if (isL2 && i == 0) { cn = 0.f; hn = 0.f; }   // L2 lag: h2(-1)=0
        c = cn;
        if (wr) hs[i & 1][slot] = hn;

        asm volatile("s_waitcnt lgkmcnt(0)" ::: "memory");
        __builtin_amdgcn_s_barrier();
        __builtin_amdgcn_sched_barrier(0);

        // broadcast-read h(i) [and h2(i-1), wave-3 only] for next iteration
        const float* hb = hs[i & 1];
        #pragma unroll
        for (int m = 0; m < 13; ++m) {
            float4 v = *(const float4*)(hb + 4 * m);
            h1v[4*m+0] = v.x; h1v[4*m+1] = v.y;
            h1v[4*m+2] = v.z; h1v[4*m+3] = v.w;
        }
        if (tid >= 192) {                         // wave-uniform: only wave 3 needs h2
            #pragma unroll
            for (int m = 0; m < 3; ++m) {
                float4 v = *(const float4*)(hb + 52 + 4 * m);
                h2v[4*m+0] = v.x; h2v[4*m+1] = v.y;
                h2v[4*m+2] = v.z; h2v[4*m+3] = v.w;
            }
        }
    }

    // ---- tail: L2 computes h2(len-1) from h1(len-1), h2(len-2)
    if (isL2) {
        float s0 = 0.f, s1 = 0.f, s2 = 0.f, s3 = 0.f;
        #pragma unroll
        for (int m = 0; m < 13; ++m) {
            s0 = fmaf(wreg[4*m+0], h1v[4*m+0], s0);
            s1 = fmaf(wreg[4*m+1], h1v[4*m+1], s1);
            s2 = fmaf(wreg[4*m+2], h1v[4*m+2], s2);
            s3 = fmaf(wreg[4*m+3], h1v[4*m+3], s3);
        }
        #pragma unroll
        for (int m = 0; m < 3; ++m) {
            s0 = fmaf(wregb[4*m+0], h2v[4*m+0], s0);
            s1 = fmaf(wregb[4*m+1], h2v[4*m+1], s1);
            s2 = fmaf(wregb[4*m+2], h2v[4*m+2], s2);
            s3 = fmaf(wregb[4*m+3], h2v[4*m+3], s3);
        }
        float gv = base2 + (s0 + s1) + (s2 + s3);
        float gi = qb<0x00>(gv);
        float gf = qb<0x55>(gv);
        float gg = qb<0xAA>(gv);
        float go = qb<0xFF>(gv);
        float cn = sigm(gf) * c + sigm(gi) * tanh_(gg);
        float hn = sigm(go) * tanh_(cn);
        if ((tid & 3) == 0) hfin[(tid - 200) >> 2] = hn;
    }
    __syncthreads();

    // ---- MLP head
    if (tid < 10) {
        float s = fc1b[tid];
        #pragma unroll
        for (int e = 0; e < 10; ++e) s = fmaf(fc1w[tid * 10 + e], hfin[e], s);
        zbuf[tid] = s > 0.f ? s : 0.f;
    }
    __syncthreads();
    if (tid == 0) {
        float s = fc2b[0];
        #pragma unroll
        for (int e = 0; e < 10; ++e) s = fmaf(fc2w[e], zbuf[e], s);
        out[b] = s;
    }
}

// ---------------------------------------------------------------------------
extern "C" void kernel_launch(void* const* d_in, const int* in_sizes, int n_in,
                              void* d_out, int out_size, void* d_ws, size_t ws_size,
                              hipStream_t stream)
{
    const int*   x     = (const int*)  d_in[0];
    const int*   len   = (const int*)  d_in[1];
    const float* emb   = (const float*)d_in[2];
    const float* W_ih1 = (const float*)d_in[3];
    const float* W_hh1 = (const float*)d_in[4];
    const float* b1    = (const float*)d_in[5];
    const float* W_ih2 = (const float*)d_in[6];
    const float* W_hh2 = (const float*)d_in[7];
    const float* b2    = (const float*)d_in[8];
    const float* fc1w  = (const float*)d_in[9];
    const float* fc1b  = (const float*)d_in[10];
    const float* fc2w  = (const float*)d_in[11];
    const float* fc2b  = (const float*)d_in[12];
    float* out = (float*)d_out;

    const size_t btg_bytes = (size_t)NPAD * KPD * sizeof(unsigned);   // 505856
    const size_t b1p_off = btg_bytes;
    const size_t head = (b1p_off + NPAD * sizeof(float) + 255) & ~255ull;
    const size_t per_b = (size_t)TT * G4 * sizeof(float);             // 409600

    unsigned* Btg = (unsigned*)d_ws;
    float*    b1p = (float*)((char*)d_ws + b1p_off);
    float*    G1  = (float*)((char*)d_ws + head);

    size_t avail = ws_size > head ? ws_size - head : 0;
    int chunk = (int)(avail / per_b);
    if (chunk < 1) chunk = 1;
    if (chunk > BB) chunk = BB;

    wtrans_kernel<<<dim3(EE), dim3(256), 0, stream>>>(W_ih1, b1, Btg, b1p);

    for (int b0 = 0; b0 < BB; b0 += chunk) {
        int nb = (BB - b0) < chunk ? (BB - b0) : chunk;
        proj_kernel<<<dim3(TT / 64, nb), dim3(256), 0, stream>>>(
            x, len, emb, Btg, b1p, G1, b0);
        lstm_kernel<<<dim3(nb), dim3(256), 0, stream>>>(
            len, W_hh1, W_ih2, W_hh2, b2, fc1w, fc1b, fc2w, fc2b, G1, out, b0);
    }
}